// Round 11
// baseline (244.829 us; speedup 1.0000x reference)
//
#include <hip/hip_runtime.h>

#define N 4096
#define NITER 100
// Mr = -(C/maxC)/0.05 in [-20,0]; q16 = round((C/maxC)*65535); Mr ~= -q16*DSTEP
#define DSTEP (20.0f / 65535.0f)
#define LOG2E 1.44269504088896340736f
#define DSTEP2 (DSTEP * LOG2E)
#define TOL 1e-3f        // lambda~0.45: residual ~8e-4 on potentials -> plan err ~8e-9 << 7e-8 slack
#define NB 256
#define NT 1024
#define ROWS 16                      // rows owned per block, u16-quantized in LDS
#define TILE_BYTES (ROWS * N * 2)    // 128 KiB

typedef unsigned short u16;

// Cross-XCD-coherent accessors (per-XCD L2 NOT coherent; agent-scope atomics
// hit the device coherence point). ALL cross-block traffic uses these.
// 32-bit ONLY (R7: 64-bit agent atomics regressed). NO SOR (R7/R8: slower).
__device__ __forceinline__ float aload(const float* p) {
    return __hip_atomic_load(p, __ATOMIC_RELAXED, __HIP_MEMORY_SCOPE_AGENT);
}
__device__ __forceinline__ void astore(float* p, float x) {
    __hip_atomic_store(p, x, __ATOMIC_RELAXED, __HIP_MEMORY_SCOPE_AGENT);
}
__device__ __forceinline__ void astore_rel(float* p, float x) {
    __hip_atomic_store(p, x, __ATOMIC_RELEASE, __HIP_MEMORY_SCOPE_AGENT);
}
__device__ __forceinline__ int aloadi_acq(const int* p) {
    return __hip_atomic_load(p, __ATOMIC_ACQUIRE, __HIP_MEMORY_SCOPE_AGENT);
}

__device__ __forceinline__ float fexp2(float x) {
#if __has_builtin(__builtin_amdgcn_exp2f)
    return __builtin_amdgcn_exp2f(x);        // raw v_exp_f32
#else
    return __expf(x * 0.6931471805599453f);  // exp(x*ln2) == 2^x
#endif
}

// Flag-slot all-arrive wait: NB one-shot slots (memset 0xFF each launch =
// sentinel). Arriving block release-stores a non-sentinel float to its own
// slot (no same-address RMW contention); wave 0 polls all 256 with acquire
// loads (lane i owns ints 4i..4i+3), block released via syncthreads.
__device__ __forceinline__ void waitslots(const float* f) {
    if (threadIdx.x < 64) {
        const int* fi = (const int*)f;
        const int i4 = threadIdx.x * 4;
        for (;;) {
            bool ok = (aloadi_acq(fi + i4 + 0) != -1) & (aloadi_acq(fi + i4 + 1) != -1) &
                      (aloadi_acq(fi + i4 + 2) != -1) & (aloadi_acq(fi + i4 + 3) != -1);
            if (__all(ok)) break;
            __builtin_amdgcn_s_sleep(1);
        }
    }
    __syncthreads();
}

// Grid-uniform max over NB floats (every block reduces the same data in the
// same order -> identical result everywhere). scratch = 16-float LDS.
__device__ __forceinline__ float maxall(const float* f, float* scratch) {
    const int t = threadIdx.x, lane = t & 63, wave = t >> 6;
    float d = aload(&f[t & (NB - 1)]);
#pragma unroll
    for (int off = 32; off; off >>= 1) d = fmaxf(d, __shfl_down(d, off));
    if (lane == 0) scratch[wave] = d;
    __syncthreads();
    float m = scratch[0];
#pragma unroll
    for (int w = 1; w < 16; ++w) m = fmaxf(m, scratch[w]);
    __syncthreads();
    return m;
}

// One persistent co-resident kernel (R9/R10 structure; flag-slot barriers):
//   phase 0: v-init + own-rows max -> fmax slot wait (doubles as v publish)
//   phase 1: quantize own 16 rows into LDS (block-local, no barrier)
//   loop: A (u-update + col partials) -> partReady[it] wait
//         B (reduce -> v-update); ddel[it] release IS the barrier+data
//         -> wait, uniform max -> break if < TOL
//   final: out rows = exp(-q*DSTEP + u + v) from LDS tile
__global__ __launch_bounds__(NT) void ot_all(const float* __restrict__ p,
                                             const float* __restrict__ q,
                                             const float* __restrict__ C,
                                             float* fmax_arr,
                                             float* partReady,
                                             float* ddel,
                                             float* v,
                                             float* part,
                                             float* __restrict__ out) {
    extern __shared__ u16 tile[];        // [ROWS][N] = 128 KiB
    const int t = threadIdx.x;
    const int b = blockIdx.x;
    const int lane = t & 63;
    const int wave = t >> 6;             // 0..15
    const int gid = b * NT + t;
    const int r0 = b * ROWS;             // owned rows (phase A / final)
    const int c0 = b * 16;               // owned cols (phase B)
    const int j0 = t * 4;                // per-thread col slice

    __shared__ float sred[4][16];
    __shared__ float wbc[4];
    __shared__ float s2[16][16];
    __shared__ float dm[16];
    __shared__ float lp[ROWS], pp[ROWS], lq[16], su[ROWS];

    // ---------------- phase 0: v-init + max over OWN rows ----------------
    {
        if (gid < N) astore(&v[gid], 0.f);   // published by the fmax release below
        const float4* Crow = (const float4*)(C + (size_t)r0 * N);
        float m = 0.f;
        for (int i = t; i < ROWS * N / 4; i += NT) {
            float4 c = Crow[i];
            m = fmaxf(m, fmaxf(fmaxf(c.x, c.y), fmaxf(c.z, c.w)));
        }
#pragma unroll
        for (int off = 32; off; off >>= 1) m = fmaxf(m, __shfl_down(m, off));
        if (lane == 0) dm[wave] = m;
        __syncthreads();
        if (t == 0) {
            m = dm[0];
#pragma unroll
            for (int i = 1; i < 16; ++i) m = fmaxf(m, dm[i]);
            astore_rel(&fmax_arr[b], m);     // arrival flag + data (C >= 0, bits != -1)
        }
        __syncthreads();                     // dm reuse safety before maxall
    }
    waitslots(fmax_arr);
    const float qmul = 65535.0f / maxall(fmax_arr, dm);

    // ---------------- phase 1: quantize own rows into LDS (block-local) ----------------
    {
        const float4* Crow = (const float4*)(C + (size_t)r0 * N);
        uint2* T2 = (uint2*)tile;
        for (int i = t; i < ROWS * N / 4; i += NT) {
            float4 a = Crow[i];
            uint2 o;
            o.x = min(65535u, __float2uint_rn(a.x * qmul)) | (min(65535u, __float2uint_rn(a.y * qmul)) << 16);
            o.y = min(65535u, __float2uint_rn(a.z * qmul)) | (min(65535u, __float2uint_rn(a.w * qmul)) << 16);
            T2[i] = o;
        }
        if (t < ROWS) {
            float pv = p[r0 + t];
            pp[t] = pv;
            lp[t] = __logf(pv);
            lq[t] = __logf(q[c0 + t]);
            su[t] = 0.f;
        }
        __syncthreads();
    }
    float vreg = 0.f;      // own col's v (valid for t<16; only this block writes it)

    // ---------------- Sinkhorn iterations (plain, Gauss-Seidel) ----------------
    for (int it = 0; it < NITER; ++it) {
        // ---- phase A: S_r = sum_j exp(Mr+v_j); u_r = logp_r - log S_r;
        //      colpart_j += t_rj * (p_r/S_r) ----
        float vv2[4];
#pragma unroll
        for (int k = 0; k < 4; ++k) vv2[k] = aload(&v[j0 + k]) * LOG2E;
        float ca[4] = {0.f, 0.f, 0.f, 0.f};

        for (int ch = 0; ch < 4; ++ch) {
            const int rl = ch * 4;
            float tq[4][4], sp[4];
#pragma unroll
            for (int r = 0; r < 4; ++r) {
                uint2 a = *(const uint2*)(tile + (size_t)(rl + r) * N + j0);
                float e0 = fexp2(fmaf((float)(a.x & 0xffffu), -DSTEP2, vv2[0]));
                float e1 = fexp2(fmaf((float)(a.x >> 16),     -DSTEP2, vv2[1]));
                float e2 = fexp2(fmaf((float)(a.y & 0xffffu), -DSTEP2, vv2[2]));
                float e3 = fexp2(fmaf((float)(a.y >> 16),     -DSTEP2, vv2[3]));
                tq[r][0] = e0; tq[r][1] = e1; tq[r][2] = e2; tq[r][3] = e3;
                sp[r] = (e0 + e1) + (e2 + e3);
            }
#pragma unroll
            for (int r = 0; r < 4; ++r) {
                float s = sp[r];
#pragma unroll
                for (int off = 32; off; off >>= 1) s += __shfl_down(s, off);
                if (lane == 0) sred[r][wave] = s;
            }
            __syncthreads();
            if (wave < 4) {  // wave w finalizes local row rl+w
                float s = (lane < 16) ? sred[wave][lane] : 0.f;
                s += __shfl_down(s, 8);
                s += __shfl_down(s, 4);
                s += __shfl_down(s, 2);
                s += __shfl_down(s, 1);
                if (lane == 0) {
                    wbc[wave] = pp[rl + wave] / s;             // exp(u_new_r)
                    su[rl + wave] = lp[rl + wave] - __logf(s); // u_new_r (block-local)
                }
            }
            __syncthreads();
#pragma unroll
            for (int r = 0; r < 4; ++r) {
                const float w = wbc[r];
#pragma unroll
                for (int k = 0; k < 4; ++k) ca[k] = fmaf(tq[r][k], w, ca[k]);
            }
        }
#pragma unroll
        for (int k = 0; k < 4; ++k) astore(&part[(size_t)b * N + j0 + k], ca[k]);
        __syncthreads();                                  // drain block's part stores
        if (t == 0) astore_rel(&partReady[it * NB + b], 1.0f);
        waitslots(&partReady[it * NB]);

        // ---- phase B: v_j = logq_j + v_old_j - log( sum_b part[b][j] ) for 16 owned cols ----
        float dblk = 0.f;
        {
            const int cl = t & 15;       // col-local
            const int ch = t >> 4;       // 0..63 part-row group
            const int c = c0 + cl;
            float s = 0.f;
#pragma unroll
            for (int k = 0; k < 4; ++k) s += aload(&part[(size_t)(ch + 64 * k) * N + c]);
            s += __shfl_down(s, 16);
            s += __shfl_down(s, 32);
            if (lane < 16) s2[cl][wave] = s;
            __syncthreads();
            if (t < 16) {
                float tot = 0.f;
#pragma unroll
                for (int w = 0; w < 16; ++w) tot += s2[t][w];
                const float vn = lq[t] + vreg - __logf(tot);
                astore(&v[c0 + t], vn);
                float d = fabsf(vn - vreg);
                vreg = vn;
                d = fmaxf(d, __shfl_down(d, 8));
                d = fmaxf(d, __shfl_down(d, 4));
                d = fmaxf(d, __shfl_down(d, 2));
                d = fmaxf(d, __shfl_down(d, 1));
                dblk = d;                // valid on t==0
            }
        }
        __syncthreads();                                  // drain block's v stores
        if (t == 0) astore_rel(&ddel[it * NB + b], dblk); // arrival flag + data (d>=0, bits != -1)
        waitslots(&ddel[it * NB]);
        const float m = maxall(&ddel[it * NB], dm);       // grid-uniform
        if (m < TOL) break;
    }

    // ---------------- final: out rows from LDS tile + su + coherent v ----------------
    {
        float vvl[4];
#pragma unroll
        for (int k = 0; k < 4; ++k) vvl[k] = aload(&v[j0 + k]) * LOG2E;
#pragma unroll 4
        for (int r = 0; r < ROWS; ++r) {
            const float uul = su[r] * LOG2E;
            uint2 a = *(const uint2*)(tile + (size_t)r * N + j0);
            float4 o;
            o.x = fexp2(fmaf((float)(a.x & 0xffffu), -DSTEP2, uul + vvl[0]));
            o.y = fexp2(fmaf((float)(a.x >> 16),     -DSTEP2, uul + vvl[1]));
            o.z = fexp2(fmaf((float)(a.y & 0xffffu), -DSTEP2, uul + vvl[2]));
            o.w = fexp2(fmaf((float)(a.y >> 16),     -DSTEP2, uul + vvl[3]));
            *(float4*)(out + (size_t)(r0 + r) * N + j0) = o;
        }
    }
}

extern "C" void kernel_launch(void* const* d_in, const int* in_sizes, int n_in,
                              void* d_out, int out_size, void* d_ws, size_t ws_size,
                              hipStream_t stream) {
    const float* p = (const float*)d_in[0];
    const float* q = (const float*)d_in[1];
    const float* C = (const float*)d_in[2];
    float* out = (float*)d_out;

    float* W = (float*)d_ws;
    float* fmax_arr  = W;                          // NB            (sentinel 0xFF..)
    float* partReady = W + NB;                     // NITER*NB      (sentinel)
    float* ddel      = W + NB + NITER * NB;        // NITER*NB      (sentinel)
    float* v         = W + NB + 2 * NITER * NB;    // N (init'd in-kernel)
    float* part = (float*)((char*)d_ws + 256 * 1024);   // NB x N f32 = 4 MB (flag-guarded)

    // sentinel-fill all flag slots: (NB + 2*NITER*NB) floats
    hipMemsetAsync(d_ws, 0xFF, (size_t)(NB + 2 * NITER * NB) * sizeof(float), stream);

    hipFuncSetAttribute((const void*)ot_all, hipFuncAttributeMaxDynamicSharedMemorySize, TILE_BYTES);

    void* args[] = {(void*)&p, (void*)&q, (void*)&C, (void*)&fmax_arr,
                    (void*)&partReady, (void*)&ddel, (void*)&v, (void*)&part, (void*)&out};
    hipLaunchCooperativeKernel((void*)ot_all, dim3(NB), dim3(NT), args, TILE_BYTES, stream);
}

// Round 12
// 210.251 us; speedup vs baseline: 1.1645x; 1.1645x over previous
//
#include <hip/hip_runtime.h>

#define N 4096
#define NITER 100
#define LOG2E 1.44269504088896340736f
#define TOL 3e-4f        // R10/R11: K=12 at both 3e-4 and 1e-3; keep margin
#define NB 256
#define NT 1024
#define ROWS 16                      // rows owned per block, u16-quantized in LDS
#define TILE_BYTES (ROWS * N * 2)    // 128 KiB
#define GRPS 8
#define BPG 32                       // blocks per group
#define EVSTRIDE 144                 // ints per event: 8 grp counters @16-int spacing + root @128

typedef unsigned short u16;

// Cross-XCD-coherent accessors (per-XCD L2 NOT coherent). ALL cross-block data
// uses 32-bit relaxed agent atomics (R7: 64-bit regressed; R5: plain loads see
// stale L2). Ordering via release/acquire chains in the barrier.
__device__ __forceinline__ float aload(const float* p) {
    return __hip_atomic_load(p, __ATOMIC_RELAXED, __HIP_MEMORY_SCOPE_AGENT);
}
__device__ __forceinline__ void astore(float* p, float x) {
    __hip_atomic_store(p, x, __ATOMIC_RELAXED, __HIP_MEMORY_SCOPE_AGENT);
}

__device__ __forceinline__ float fexp2(float x) {
#if __has_builtin(__builtin_amdgcn_exp2f)
    return __builtin_amdgcn_exp2f(x);        // raw v_exp_f32
#else
    return __expf(x * 0.6931471805599453f);  // exp(x*ln2) == 2^x
#endif
}

// Hierarchical one-shot barrier (event-indexed slots, memset-0 per launch).
// Arrival: acq_rel fetch_add on own group's line (32 RMWs/line, 8 lines in
// parallel); group-last acq_rel-adds the root. Wait: spin ONE address (root)
// with acquire + s_sleep (R11 lesson: multi-address polling congests the
// coherence point). acq_rel hops keep release/acquire transitivity:
// any block's pre-barrier stores happen-before any post-wait access.
__device__ __forceinline__ void gbar_arrive(int* bar, int e) {   // t==0 only
    int* base = bar + e * EVSTRIDE;
    const int g = (int)(blockIdx.x >> 5);
    int r = __hip_atomic_fetch_add(base + g * 16, 1, __ATOMIC_ACQ_REL, __HIP_MEMORY_SCOPE_AGENT);
    if (r == BPG - 1)
        __hip_atomic_fetch_add(base + 128, 1, __ATOMIC_ACQ_REL, __HIP_MEMORY_SCOPE_AGENT);
}
__device__ __forceinline__ void gbar_wait(int* bar, int e) {     // t==0 only
    const int* root = bar + e * EVSTRIDE + 128;
    while (__hip_atomic_load(root, __ATOMIC_ACQUIRE, __HIP_MEMORY_SCOPE_AGENT) < GRPS)
        __builtin_amdgcn_s_sleep(1);
}
__device__ __forceinline__ void gbar(int* bar, int e) {
    __syncthreads();
    if (threadIdx.x == 0) { gbar_arrive(bar, e); gbar_wait(bar, e); }
    __syncthreads();
}

// One persistent co-resident kernel (R10 skeleton):
//   phase 0: v-init + own-rows max -> publish fmax[b] -> ARRIVE(e0)
//            -> quantize own rows into LDS w/ LOCAL max (overlaps barrier)
//            -> WAIT(e0) -> reduce fmax -> per-block dequant scale
//   loop: A (u-update + col partials) -> gbar(ePart)
//         B (reduce partials -> v-update, ddel[b])   -> gbar(eDdel)
//         wave0 reduces ddel -> uniform m -> break if < TOL
//   final: out rows = exp(Mr + u + v) from LDS tile
__global__ __launch_bounds__(NT) void ot_all(const float* __restrict__ p,
                                             const float* __restrict__ q,
                                             const float* __restrict__ C,
                                             int* bar,
                                             float* fmax_arr,
                                             float* ddel,
                                             float* v,
                                             float* part,
                                             float* __restrict__ out) {
    extern __shared__ u16 tile[];        // [ROWS][N] = 128 KiB
    const int t = threadIdx.x;
    const int b = blockIdx.x;
    const int lane = t & 63;
    const int wave = t >> 6;             // 0..15
    const int gid = b * NT + t;
    const int r0 = b * ROWS;             // owned rows (phase A / final)
    const int c0 = b * 16;               // owned cols (phase B)
    const int j0 = t * 4;                // per-thread col slice

    __shared__ float sred[4][16];
    __shared__ float wbc[4];
    __shared__ float s2[16][16];
    __shared__ float dm[16];
    __shared__ float lp[ROWS], pp[ROWS], lq[16], su[ROWS];
    __shared__ float sMown, sMaxC, sM;

    // ---------------- phase 0: v-init + own-rows max; arrive early ----------------
    if (gid < N) astore(&v[gid], 0.f);       // ordered by block 0-3's e0 release
    {
        const float4* Crow = (const float4*)(C + (size_t)r0 * N);
        float m = 0.f;
        for (int i = t; i < ROWS * N / 4; i += NT) {
            float4 c = Crow[i];
            m = fmaxf(m, fmaxf(fmaxf(c.x, c.y), fmaxf(c.z, c.w)));
        }
#pragma unroll
        for (int off = 32; off; off >>= 1) m = fmaxf(m, __shfl_down(m, off));
        if (lane == 0) dm[wave] = m;
        __syncthreads();
        if (t == 0) {
            m = dm[0];
#pragma unroll
            for (int i = 1; i < 16; ++i) m = fmaxf(m, dm[i]);
            sMown = m;
            astore(&fmax_arr[b], m);         // ordered by the acq_rel arrive below
            gbar_arrive(bar, 0);
        }
        __syncthreads();                     // sMown visible block-wide
    }

    // ---------------- phase 1: quantize own rows w/ LOCAL max (overlaps e0) ----------------
    {
        const float qmul = 65535.0f / sMown; // finer grid than global-max quant
        const float4* Crow = (const float4*)(C + (size_t)r0 * N);
        uint2* T2 = (uint2*)tile;
        for (int i = t; i < ROWS * N / 4; i += NT) {
            float4 a = Crow[i];
            uint2 o;
            o.x = min(65535u, __float2uint_rn(a.x * qmul)) | (min(65535u, __float2uint_rn(a.y * qmul)) << 16);
            o.y = min(65535u, __float2uint_rn(a.z * qmul)) | (min(65535u, __float2uint_rn(a.w * qmul)) << 16);
            T2[i] = o;
        }
        if (t < ROWS) {
            float pv = p[r0 + t];
            pp[t] = pv;
            lp[t] = __logf(pv);
            lq[t] = __logf(q[c0 + t]);
            su[t] = 0.f;
        }
    }
    __syncthreads();
    if (t == 0) gbar_wait(bar, 0);
    __syncthreads();
    if (wave == 0) {                         // reduce global max from 256 slots
        float d = fmaxf(fmaxf(aload(&fmax_arr[lane]), aload(&fmax_arr[64 + lane])),
                        fmaxf(aload(&fmax_arr[128 + lane]), aload(&fmax_arr[192 + lane])));
#pragma unroll
        for (int off = 32; off; off >>= 1) d = fmaxf(d, __shfl_down(d, off));
        if (lane == 0) sMaxC = d;
    }
    __syncthreads();
    // Mr = -(C/maxC)/0.05; C ~= q16 * m_own/65535 -> Mr ~= -q16 * ndstep (exp2 domain)
    const float ndstep = -(20.0f / 65535.0f) * (sMown / sMaxC) * LOG2E;
    float vreg = 0.f;      // own col's v (valid for t<16; only this block writes it)

    // ---------------- Sinkhorn iterations (plain Gauss-Seidel; NO SOR: R7/R8) ----------------
    for (int it = 0; it < NITER; ++it) {
        // ---- phase A: S_r = sum_j exp(Mr+v_j); u_r = logp_r - log S_r;
        //      colpart_j += t_rj * (p_r/S_r) ----
        float vv2[4];
#pragma unroll
        for (int k = 0; k < 4; ++k) vv2[k] = aload(&v[j0 + k]) * LOG2E;
        float ca[4] = {0.f, 0.f, 0.f, 0.f};

        for (int ch = 0; ch < 4; ++ch) {
            const int rl = ch * 4;
            float tq[4][4], sp[4];
#pragma unroll
            for (int r = 0; r < 4; ++r) {
                uint2 a = *(const uint2*)(tile + (size_t)(rl + r) * N + j0);
                float e0 = fexp2(fmaf((float)(a.x & 0xffffu), ndstep, vv2[0]));
                float e1 = fexp2(fmaf((float)(a.x >> 16),     ndstep, vv2[1]));
                float e2 = fexp2(fmaf((float)(a.y & 0xffffu), ndstep, vv2[2]));
                float e3 = fexp2(fmaf((float)(a.y >> 16),     ndstep, vv2[3]));
                tq[r][0] = e0; tq[r][1] = e1; tq[r][2] = e2; tq[r][3] = e3;
                sp[r] = (e0 + e1) + (e2 + e3);
            }
#pragma unroll
            for (int r = 0; r < 4; ++r) {
                float s = sp[r];
#pragma unroll
                for (int off = 32; off; off >>= 1) s += __shfl_down(s, off);
                if (lane == 0) sred[r][wave] = s;
            }
            __syncthreads();
            if (wave < 4) {  // wave w finalizes local row rl+w
                float s = (lane < 16) ? sred[wave][lane] : 0.f;
                s += __shfl_down(s, 8);
                s += __shfl_down(s, 4);
                s += __shfl_down(s, 2);
                s += __shfl_down(s, 1);
                if (lane == 0) {
                    wbc[wave] = pp[rl + wave] / s;             // exp(u_new_r)
                    su[rl + wave] = lp[rl + wave] - __logf(s); // u_new_r (block-local)
                }
            }
            __syncthreads();
#pragma unroll
            for (int r = 0; r < 4; ++r) {
                const float w = wbc[r];
#pragma unroll
                for (int k = 0; k < 4; ++k) ca[k] = fmaf(tq[r][k], w, ca[k]);
            }
        }
#pragma unroll
        for (int k = 0; k < 4; ++k) astore(&part[(size_t)b * N + j0 + k], ca[k]);
        gbar(bar, 1 + 2 * it);

        // ---- phase B: v_j = logq_j + v_old_j - log( sum_b part[b][j] ) for 16 owned cols ----
        {
            const int cl = t & 15;       // col-local
            const int ch = t >> 4;       // 0..63 part-row group
            const int c = c0 + cl;
            float s = 0.f;
#pragma unroll
            for (int k = 0; k < 4; ++k) s += aload(&part[(size_t)(ch + 64 * k) * N + c]);
            s += __shfl_down(s, 16);
            s += __shfl_down(s, 32);
            if (lane < 16) s2[cl][wave] = s;
            __syncthreads();
            if (t < 16) {
                float tot = 0.f;
#pragma unroll
                for (int w = 0; w < 16; ++w) tot += s2[t][w];
                const float vn = lq[t] + vreg - __logf(tot);
                astore(&v[c0 + t], vn);
                float d = fabsf(vn - vreg);
                vreg = vn;
                d = fmaxf(d, __shfl_down(d, 8));
                d = fmaxf(d, __shfl_down(d, 4));
                d = fmaxf(d, __shfl_down(d, 2));
                d = fmaxf(d, __shfl_down(d, 1));
                if (t == 0) astore(&ddel[it * NB + b], d);   // own slot, relaxed
            }
        }
        gbar(bar, 2 + 2 * it);

        // ---- wave0 reduces published ddel -> grid-uniform m ----
        if (wave == 0) {
            const float* dd = ddel + it * NB;
            float d = fmaxf(fmaxf(aload(dd + lane), aload(dd + 64 + lane)),
                            fmaxf(aload(dd + 128 + lane), aload(dd + 192 + lane)));
#pragma unroll
            for (int off = 32; off; off >>= 1) d = fmaxf(d, __shfl_down(d, off));
            if (lane == 0) sM = d;
        }
        __syncthreads();
        if (sM < TOL) break;    // identical data/order everywhere -> uniform
    }

    // ---------------- final: out rows from LDS tile + su + coherent v ----------------
    {
        float vvl[4];
#pragma unroll
        for (int k = 0; k < 4; ++k) vvl[k] = aload(&v[j0 + k]) * LOG2E;
#pragma unroll 4
        for (int r = 0; r < ROWS; ++r) {
            const float uul = su[r] * LOG2E;
            uint2 a = *(const uint2*)(tile + (size_t)r * N + j0);
            float4 o;
            o.x = fexp2(fmaf((float)(a.x & 0xffffu), ndstep, uul + vvl[0]));
            o.y = fexp2(fmaf((float)(a.x >> 16),     ndstep, uul + vvl[1]));
            o.z = fexp2(fmaf((float)(a.y & 0xffffu), ndstep, uul + vvl[2]));
            o.w = fexp2(fmaf((float)(a.y >> 16),     ndstep, uul + vvl[3]));
            *(float4*)(out + (size_t)(r0 + r) * N + j0) = o;
        }
    }
}

extern "C" void kernel_launch(void* const* d_in, const int* in_sizes, int n_in,
                              void* d_out, int out_size, void* d_ws, size_t ws_size,
                              hipStream_t stream) {
    const float* p = (const float*)d_in[0];
    const float* q = (const float*)d_in[1];
    const float* C = (const float*)d_in[2];
    float* out = (float*)d_out;

    char* base = (char*)d_ws;
    int* bar = (int*)base;                              // (1+2*NITER)*EVSTRIDE ints ~ 113 KB, memset 0
    float* fmax_arr = (float*)(base + 120 * 1024);      // NB floats (barrier-guarded, no sentinel)
    float* ddel = (float*)(base + 124 * 1024);          // NITER*NB floats (barrier-guarded)
    float* v = (float*)(base + 228 * 1024);             // N floats (init'd in-kernel)
    float* part = (float*)(base + 256 * 1024);          // NB x N f32 = 4 MB (barrier-guarded)

    hipMemsetAsync(d_ws, 0, (size_t)(1 + 2 * NITER) * EVSTRIDE * sizeof(int), stream);

    hipFuncSetAttribute((const void*)ot_all, hipFuncAttributeMaxDynamicSharedMemorySize, TILE_BYTES);

    void* args[] = {(void*)&p, (void*)&q, (void*)&C, (void*)&bar,
                    (void*)&fmax_arr, (void*)&ddel, (void*)&v, (void*)&part, (void*)&out};
    hipLaunchCooperativeKernel((void*)ot_all, dim3(NB), dim3(NT), args, TILE_BYTES, stream);
}